// Round 1
// baseline (249.523 us; speedup 1.0000x reference)
//
#include <hip/hip_runtime.h>

#define EPS 1e-5f

// ---------------------------------------------------------------------------
// K1: per-64x64-patch partial sums (sum, sumsq).
// Grid: 8192 blocks = 512 channels * 16 patches; 256 threads; 4 float4/thread.
// ---------------------------------------------------------------------------
__global__ __launch_bounds__(256) void k_patch_stats(const float4* __restrict__ x4,
                                                     float2* __restrict__ part) {
    const int P    = blockIdx.x;        // bc*16 + pr*4 + pc
    const int bc   = P >> 4;
    const int pidx = P & 15;
    const int pr   = pidx >> 2, pc = pidx & 3;
    const int t    = threadIdx.x;
    const long chan4 = (long)bc << 14;  // 16384 float4 per channel (256 rows * 64)

    float s = 0.f, ss = 0.f;
#pragma unroll
    for (int k = 0; k < 4; ++k) {
        const int q    = k * 256 + t;   // 0..1023 float4 within patch
        const int row  = q >> 4;        // 0..63
        const int col4 = q & 15;        // 0..15
        const long idx = chan4 + (long)(pr * 64 + row) * 64 + pc * 16 + col4;
        const float4 v = x4[idx];
        s  += v.x + v.y + v.z + v.w;
        ss += v.x * v.x + v.y * v.y + v.z * v.z + v.w * v.w;
    }
    // wave64 reduce
#pragma unroll
    for (int off = 32; off > 0; off >>= 1) {
        s  += __shfl_down(s, off, 64);
        ss += __shfl_down(ss, off, 64);
    }
    __shared__ float2 red[4];
    const int wave = t >> 6, lane = t & 63;
    if (lane == 0) red[wave] = make_float2(s, ss);
    __syncthreads();
    if (t == 0) {
        float S = 0.f, SS = 0.f;
#pragma unroll
        for (int i = 0; i < 4; ++i) { S += red[i].x; SS += red[i].y; }
        part[P] = make_float2(S, SS);
    }
}

// ---------------------------------------------------------------------------
// K2: aggregate patch sums -> (a = rstd, b = -mu*rstd) for 21 slots/channel:
//   slots 0..15  : level p=2 (64x64),  index pr*4+pc
//   slots 16..19 : level p=1 (128x128), index gr*2+gc
//   slot  20     : level p=0 (full 256x256)
// Grid: 512 blocks (channels) x 64 threads.
// ---------------------------------------------------------------------------
__global__ __launch_bounds__(64) void k_aggregate(const float2* __restrict__ part,
                                                  float2* __restrict__ S) {
    const int bc = blockIdx.x;
    const int t  = threadIdx.x;
    __shared__ float2 ps[16];
    if (t < 16) ps[t] = part[bc * 16 + t];
    __syncthreads();

    float sum = 0.f, sq = 0.f, n = 1.f;
    int slot = -1;
    if (t < 16) {                       // p=2
        sum = ps[t].x; sq = ps[t].y; n = 4096.f; slot = t;
    } else if (t < 20) {                // p=1: group (gr,gc) -> patches 8gr+2gc + {0,1,4,5}
        const int g = t - 16, gr = g >> 1, gc = g & 1;
        const int b = 8 * gr + 2 * gc;
        sum = ps[b].x + ps[b + 1].x + ps[b + 4].x + ps[b + 5].x;
        sq  = ps[b].y + ps[b + 1].y + ps[b + 4].y + ps[b + 5].y;
        n = 16384.f; slot = 16 + g;
    } else if (t == 20) {               // p=0
#pragma unroll
        for (int i = 0; i < 16; ++i) { sum += ps[i].x; sq += ps[i].y; }
        n = 65536.f; slot = 20;
    }
    if (slot >= 0) {
        const float mu   = sum / n;
        const float var  = sq / n - mu * mu;
        const float rstd = rsqrtf(var + EPS);
        S[bc * 21 + slot] = make_float2(rstd, -mu * rstd);
    }
}

// ---------------------------------------------------------------------------
// K3: elementwise output. out = x * (0.5 + 0.5 * (lwA*s2 + lwB*s1 + lwC*s0))
// Grid: 32768 blocks x 256 threads, one float4 per thread.
// ---------------------------------------------------------------------------
__device__ __forceinline__ float sigm(float t) {
    return __builtin_amdgcn_rcpf(1.f + __expf(-t));
}

__global__ __launch_bounds__(256) void k_out(const float4* __restrict__ x4,
                                             const float2* __restrict__ S,
                                             const float* __restrict__ lw,
                                             float4* __restrict__ out4) {
    const long i = (long)blockIdx.x * 256 + threadIdx.x;  // float4 index

    // softmax of the 3 level weights (wave-uniform -> scalar path)
    const float w0 = lw[0], w1 = lw[1], w2 = lw[2];
    const float m  = fmaxf(w0, fmaxf(w1, w2));
    const float e0 = __expf(w0 - m), e1 = __expf(w1 - m), e2 = __expf(w2 - m);
    const float inv = __builtin_amdgcn_rcpf(e0 + e1 + e2);
    const float lwA = e0 * inv;   // pairs with p=2 (64x64)
    const float lwB = e1 * inv;   // pairs with p=1 (128x128)
    const float lwC = e2 * inv;   // pairs with p=0 (full)

    const int bc = (int)(i >> 14);
    const int f  = (int)(i & 16383);
    const int w4 = f & 63;        // float4 column 0..63
    const int h  = f >> 6;        // row 0..255
    const float2* Sc = S + bc * 21;
    const float2 s2 = Sc[(h >> 6) * 4 + (w4 >> 4)];
    const float2 s1 = Sc[16 + (h >> 7) * 2 + (w4 >> 5)];
    const float2 s0 = Sc[20];

    const float4 v = x4[i];
    float4 r;
#define ELT(comp)                                                              \
    {                                                                          \
        const float xv  = v.comp;                                              \
        const float acc = lwA * sigm(fmaf(xv, s2.x, s2.y))                     \
                        + lwB * sigm(fmaf(xv, s1.x, s1.y))                     \
                        + lwC * sigm(fmaf(xv, s0.x, s0.y));                    \
        r.comp = xv * (0.5f + 0.5f * acc);                                     \
    }
    ELT(x) ELT(y) ELT(z) ELT(w)
#undef ELT
    out4[i] = r;
}

extern "C" void kernel_launch(void* const* d_in, const int* in_sizes, int n_in,
                              void* d_out, int out_size, void* d_ws, size_t ws_size,
                              hipStream_t stream) {
    const float* x  = (const float*)d_in[0];
    const float* lw = (const float*)d_in[1];
    float* out      = (float*)d_out;

    float2* part = (float2*)d_ws;      // 8192 float2 (64 KB)
    float2* S    = part + 8192;        // 512*21 = 10752 float2 (86 KB)

    k_patch_stats<<<8192, 256, 0, stream>>>((const float4*)x, part);
    k_aggregate<<<512, 64, 0, stream>>>(part, S);
    k_out<<<32768, 256, 0, stream>>>((const float4*)x, S, lw, (float4*)out);
}